// Round 18
// baseline (179.344 us; speedup 1.0000x reference)
//
#include <hip/hip_runtime.h>
#include <math.h>

typedef __attribute__((ext_vector_type(4))) float f32x4;
typedef __attribute__((ext_vector_type(16))) float f32x16;
typedef __attribute__((ext_vector_type(8))) short bf16x8;
typedef __attribute__((ext_vector_type(4))) unsigned short us4;
typedef __attribute__((ext_vector_type(4))) unsigned int u32x4;

#define T_SEQ 2048
#define NH 16
#define HD 64
#define CDIM 1024

__device__ __forceinline__ unsigned short f2bf(float f) {
  unsigned int u = __float_as_uint(f);
  u += 0x7fffu + ((u >> 16) & 1u);
  return (unsigned short)(u >> 16);
}

__device__ __forceinline__ f32x16 zero16() {
  f32x16 z;
#pragma unroll
  for (int i = 0; i < 16; ++i) z[i] = 0.0f;
  return z;
}

// global -> LDS direct (16B/lane, wave-uniform LDS base + lane*16)
#define GLOAD_LDS(g, l)                                                   \
  __builtin_amdgcn_global_load_lds(                                       \
      (const __attribute__((address_space(1))) unsigned int*)(g),         \
      (__attribute__((address_space(3))) unsigned int*)(l), 16, 0, 0)

// ---------------- cast x: fp32 -> bf16 ----------------
__global__ __launch_bounds__(256) void cast_x_kernel(const float* __restrict__ src,
                                                     unsigned short* __restrict__ dst,
                                                     int n4) {
  int i = blockIdx.x * 256 + threadIdx.x;
  if (i >= n4) return;
  f32x4 v = reinterpret_cast<const f32x4*>(src)[i];
  us4 o;
#pragma unroll
  for (int j = 0; j < 4; ++j) o[j] = f2bf(v[j]);
  reinterpret_cast<us4*>(dst)[i] = o;
}

// -------- fused transpose+cast of all 3 weights: W[K][N] fp32 -> W^T bf16 ----
__global__ __launch_bounds__(256) void transpose_cast_all_kernel(
    const float* __restrict__ Wq, const float* __restrict__ Wkv,
    const float* __restrict__ Wc, unsigned short* __restrict__ WT,
    unsigned short* __restrict__ WcT) {
  __shared__ float tile[32][33];
  const int nglob = blockIdx.x * 32;
  const float* src;
  unsigned short* dst;
  int ldsrc, n0;
  if (nglob < 1024) {
    src = Wq; dst = WT; ldsrc = 1024; n0 = nglob;
  } else if (nglob < 3072) {
    src = Wkv; dst = WT + 1024 * 1024; ldsrc = 2048; n0 = nglob - 1024;
  } else {
    src = Wc; dst = WcT; ldsrc = 1024; n0 = nglob - 3072;
  }
  const int k0 = blockIdx.y * 32;
  const int tx = threadIdx.x & 31, ty = threadIdx.x >> 5;  // 32x8
#pragma unroll
  for (int r = 0; r < 4; ++r)
    tile[ty + r * 8][tx] = src[(size_t)(k0 + ty + r * 8) * ldsrc + n0 + tx];
  __syncthreads();
#pragma unroll
  for (int r = 0; r < 4; ++r)
    dst[(size_t)(n0 + ty + r * 8) * 1024 + k0 + tx] = f2bf(tile[tx][ty + r * 8]);
}

// ---------------- RoPE table: cos/sin [T][32] fp32 ----------------
__global__ __launch_bounds__(256) void rope_table_kernel(float* __restrict__ cost,
                                                         float* __restrict__ sint) {
  int idx = blockIdx.x * 256 + threadIdx.x;  // 2048*32
  int t = idx >> 5, j = idx & 31;
  double invf = pow(10000.0, -(double)j / 32.0);
  double ang = (double)t * invf;
  cost[idx] = (float)cos(ang);
  sint[idx] = (float)sin(ang);
}

// ---------------- GEMM: C[M][N] = A[M][K] * B^T[N][K], bf16 in, fp32 acc ----
// 2-phase double-buffered pipeline, BK=32 THIS ROUND (was 64): LDS 32KB ->
// ~5 blocks/CU (was 2), so the per-tile barrier drain is hidden by TLP
// (m97 regime: 874-912 TF at ~3 blocks/CU). Swizzle = R9/R10-verified BK=32
// XOR: source (lane&3)^((srow>>1)&3), read lhi^((row>>1)&3) -> 2-way
// residual (free). Pipeline-port attempts REGRESSED twice (R10, R14): this
// is a parameter change on the attested 2-phase structure, not a new schedule.
template <int MODE>
__global__ __launch_bounds__(256) void gemm_kernel(
    const unsigned short* __restrict__ A, const unsigned short* __restrict__ Bt,
    int M, int N, int K,
    unsigned short* __restrict__ qo, unsigned short* __restrict__ ko,
    unsigned short* __restrict__ vTo, const float* __restrict__ cost,
    const float* __restrict__ sint, float* __restrict__ out) {
  __shared__ __align__(16) unsigned short As[2][128 * 32];  // 2 x 8KB
  __shared__ __align__(16) unsigned short Bs[2][128 * 32];  // 2 x 8KB
  const int tid = threadIdx.x;
  const int lane = tid & 63;
  const int wave = tid >> 6;
  const int wr = wave >> 1, wc = wave & 1;
  const int m0 = blockIdx.y * 128, n0 = blockIdx.x * 128;
  const int lrow = lane & 15, lhi = lane >> 4;
  // staging: chunk = 16 rows x 64B; wave does chunks wave*2..+1 per matrix.
  const int srow = lane >> 2;                             // row in chunk
  const int scol = ((lane & 3) ^ ((srow >> 1) & 3)) * 8;  // swizzled src col

  f32x4 zero4 = {0.f, 0.f, 0.f, 0.f};
  f32x4 acc[4][4];
#pragma unroll
  for (int mi = 0; mi < 4; ++mi)
#pragma unroll
    for (int ni = 0; ni < 4; ++ni) acc[mi][ni] = zero4;

  const int ntiles = K >> 5;  // BK=32
  auto stage = [&](int bf, int kt) {
#pragma unroll
    for (int c2 = 0; c2 < 2; ++c2) {
      const int c = wave * 2 + c2;  // chunk 0..7 (16 rows x 64B each)
      GLOAD_LDS(&A[(size_t)(m0 + c * 16 + srow) * K + kt + scol], &As[bf][c * 512]);
      GLOAD_LDS(&Bt[(size_t)(n0 + c * 16 + srow) * K + kt + scol], &Bs[bf][c * 512]);
    }
  };

  stage(0, 0);
  __syncthreads();  // buf0 ready
  int cur = 0;
  for (int ti = 0; ti < ntiles; ++ti) {
    if (ti + 1 < ntiles) stage(cur ^ 1, (ti + 1) * 32);  // in flight under compute
    bf16x8 af[4], bfv[4];
#pragma unroll
    for (int i = 0; i < 4; ++i) {
      const int ra = wr * 64 + i * 16 + lrow;
      const int rb = wc * 64 + i * 16 + lrow;
      af[i] = *reinterpret_cast<const bf16x8*>(
          &As[cur][ra * 32 + (lhi ^ ((ra >> 1) & 3)) * 8]);
      bfv[i] = *reinterpret_cast<const bf16x8*>(
          &Bs[cur][rb * 32 + (lhi ^ ((rb >> 1) & 3)) * 8]);
    }
#pragma unroll
    for (int mi = 0; mi < 4; ++mi)
#pragma unroll
      for (int ni = 0; ni < 4; ++ni)
        acc[mi][ni] =
            __builtin_amdgcn_mfma_f32_16x16x32_bf16(af[mi], bfv[ni], acc[mi][ni], 0, 0, 0);
    __syncthreads();  // drains my gloads (flew under MFMA) + reads; swap safe
    cur ^= 1;
  }

  if (MODE == 0) {
#pragma unroll
    for (int mi = 0; mi < 4; ++mi)
#pragma unroll
      for (int ni = 0; ni < 4; ++ni) {
        int n = n0 + wc * 64 + ni * 16 + lrow;
#pragma unroll
        for (int r = 0; r < 4; ++r) {
          int m = m0 + wr * 64 + mi * 16 + lhi * 4 + r;
          out[(size_t)m * N + n] = acc[mi][ni][r];
        }
      }
  } else {
#pragma unroll
    for (int mi = 0; mi < 4; ++mi) {
      int mb = m0 + wr * 64 + mi * 16 + lhi * 4;  // 4 consecutive rows (t)
      int b = mb >> 11, tb = mb & (T_SEQ - 1);
#pragma unroll
      for (int ni = 0; ni < 4; ++ni) {
        int n = n0 + wc * 64 + ni * 16 + lrow;
        int sec = n >> 10;          // 0=q 1=k 2=v
        int h = (n >> 6) & 15;
        int d = n & 63;
        int bh_ = b * NH + h;
        if (sec == 2) {
          int t64 = tb >> 6, ks = (tb >> 4) & 3, hiv = (tb >> 3) & 1, e0 = tb & 7;
          int dgrp = d >> 5, lanev = hiv * 32 + (d & 31);
          us4 pk;
#pragma unroll
          for (int r = 0; r < 4; ++r) pk[r] = f2bf(acc[mi][ni][r]);
          size_t addr =
              ((((size_t)bh_ * 32 + t64) * 2 + dgrp) * 4 + ks) * 512 + lanev * 8 + e0;
          *reinterpret_cast<us4*>(&vTo[addr]) = pk;
        } else {
          int dm = d & 31;
          float sgn = (d < 32) ? -1.0f : 1.0f;
          unsigned short* dstp = (sec == 0) ? qo : ko;
          int ks = d >> 4, hiq = (d >> 3) & 1, e = d & 7;
#pragma unroll
          for (int r = 0; r < 4; ++r) {
            int t = tb + r;
            float c = cost[t * 32 + dm], s = sint[t * 32 + dm];
            float val = acc[mi][ni][r] * c + sgn * acc[mi][ni ^ 2][r] * s;
            if (sec == 0) val *= 0.125f;  // 1/sqrt(64) folded into q
            int blk = t >> 5, lane_ = hiq * 32 + (t & 31);
            dstp[(((size_t)bh_ * 64 + blk) * 4 + ks) * 512 + lane_ * 8 + e] = f2bf(val);
          }
        }
      }
    }
  }
}

// ---------------- flash attention, causal; 32x32 swapped-QK^T ----------------
// R15/R17 attested config: 8-wave/512-thread blocks, super-tile staging
// (128 keys / 32KB per stage, 2 x 64-key compute steps per barrier),
// double-buffered LDS (64KB -> 2 blocks/CU). In-register softmax; T13
// defer-max; T12 cvt_pk+permlane; setprio around MFMA. R16's pair-balanced
// variant REGRESSED: do not re-add.
__global__ __launch_bounds__(512, 2) void attn_kernel(const unsigned short* __restrict__ qg,
                                                      const unsigned short* __restrict__ kg,
                                                      const unsigned short* __restrict__ vtg,
                                                      unsigned short* __restrict__ att) {
  __shared__ __align__(16) unsigned short Ks[2][8192];  // 2 x 16KB (128 keys)
  __shared__ __align__(16) unsigned short Vs[2][8192];  // 2 x 16KB
  const int tid = threadIdx.x;
  const int lane = tid & 63;
  const int w = tid >> 6;
  const int l31 = lane & 31, hi = lane >> 5;
  const int bid = (int)blockIdx.x;          // 0..511
  const int second = bid >> 8;
  const int q = bid & 255;
  const int xcd = q & 7, g = q >> 3;
  const int bh = xcd * 8 + (g >> 2);
  const int ii = g & 3;
  const int i = second ? (7 - ii) : ii;
  const int pos = (w < 4) ? (4 * i + w) : (63 - 4 * i - (w - 4));
  const int qrow = pos * 32 + l31;
  const int myt = (pos >> 1) + 1;       // 64-key steps this wave needs
  const int maxT = 32 - 2 * i;          // block lockstep 64-key steps (even)
  const int smaxT = maxT >> 1;          // super-tiles (128 keys each)
  const unsigned short* qfp = qg + (size_t)bh * 131072;
  const unsigned short* kfp = kg + (size_t)bh * 131072;
  const unsigned short* vfp = vtg + (size_t)bh * 131072;
  const int b = bh >> 4, h = bh & 15;

  bf16x8 qf[4];
#pragma unroll
  for (int ks = 0; ks < 4; ++ks)
    qf[ks] = *reinterpret_cast<const bf16x8*>(&qfp[((size_t)pos * 4 + ks) * 512 + lane * 8]);

  f32x16 oA = zero16(), oB = zero16();
  float mrun = -3.0e38f, lrun = 0.0f;

  // super-tile T = keys 128T..128T+127 = 8192 contiguous elems (frag-major).
  auto stage = [&](int bf, int T) {
    GLOAD_LDS(&kfp[(size_t)T * 8192 + tid * 8], &Ks[bf][w * 512]);
    GLOAD_LDS(&kfp[(size_t)T * 8192 + 4096 + tid * 8], &Ks[bf][4096 + w * 512]);
    GLOAD_LDS(&vfp[(size_t)T * 8192 + tid * 8], &Vs[bf][w * 512]);
    GLOAD_LDS(&vfp[(size_t)T * 8192 + 4096 + tid * 8], &Vs[bf][4096 + w * 512]);
  };

  stage(0, 0);
  __syncthreads();
  int buf = 0;
  for (int T = 0; T < smaxT; ++T) {
    if (T + 1 < smaxT) stage(buf ^ 1, T + 1);  // 4 gloads fly under 2 steps
#pragma unroll
    for (int sub = 0; sub < 2; ++sub) {
      const int s = 2 * T + sub;  // 64-key step index
      const int off = sub * 4096;
      if (s < myt) {  // wave-uniform predicate
        f32x16 sA = zero16(), sB = zero16();
        __builtin_amdgcn_s_setprio(1);
#pragma unroll
        for (int ks = 0; ks < 4; ++ks) {
          bf16x8 ka = *reinterpret_cast<const bf16x8*>(&Ks[buf][off + ks * 512 + lane * 8]);
          bf16x8 kb =
              *reinterpret_cast<const bf16x8*>(&Ks[buf][off + (4 + ks) * 512 + lane * 8]);
          sA = __builtin_amdgcn_mfma_f32_32x32x16_bf16(ka, qf[ks], sA, 0, 0, 0);
          sB = __builtin_amdgcn_mfma_f32_32x32x16_bf16(kb, qf[ks], sB, 0, 0, 0);
        }
        __builtin_amdgcn_s_setprio(0);
        if (s == myt - 1) {  // only final step can contain future keys
          const int kvb = s * 64;
#pragma unroll
          for (int r = 0; r < 16; ++r) {
            int keyA = kvb + (r & 3) + 8 * (r >> 2) + 4 * hi;
            if (keyA > qrow) sA[r] = -1e30f;
            if (keyA + 32 > qrow) sB[r] = -1e30f;
          }
        }
        float tr[16];
#pragma unroll
        for (int k2 = 0; k2 < 16; ++k2) tr[k2] = fmaxf(sA[k2], sB[k2]);
#pragma unroll
        for (int k2 = 0; k2 < 8; ++k2) tr[k2] = fmaxf(tr[k2], tr[k2 + 8]);
#pragma unroll
        for (int k2 = 0; k2 < 4; ++k2) tr[k2] = fmaxf(tr[k2], tr[k2 + 4]);
        float tm = fmaxf(fmaxf(tr[0], tr[1]), fmaxf(tr[2], tr[3]));
        tm = fmaxf(tm, __shfl_xor(tm, 32));
        if (!__all(tm - mrun <= 8.0f)) {  // T13 defer-max
          float mnew = fmaxf(mrun, tm);
          float alpha = __expf(mrun - mnew);
          lrun *= alpha;
#pragma unroll
          for (int k2 = 0; k2 < 16; ++k2) {
            oA[k2] *= alpha;
            oB[k2] *= alpha;
          }
          mrun = mnew;
        }
#pragma unroll
        for (int k2 = 0; k2 < 16; ++k2) {
          sA[k2] = __expf(sA[k2] - mrun);
          sB[k2] = __expf(sB[k2] - mrun);
        }
        float sr[16];
#pragma unroll
        for (int k2 = 0; k2 < 16; ++k2) sr[k2] = sA[k2] + sB[k2];
#pragma unroll
        for (int k2 = 0; k2 < 8; ++k2) sr[k2] += sr[k2 + 8];
#pragma unroll
        for (int k2 = 0; k2 < 4; ++k2) sr[k2] += sr[k2 + 4];
        float lsum = (sr[0] + sr[1]) + (sr[2] + sr[3]);
        lsum += __shfl_xor(lsum, 32);
        lrun += lsum;
        // T12: P -> B-operand fragments in registers
        unsigned int ua[4], va[4], ub[4], vb[4];
#pragma unroll
        for (int m = 0; m < 4; ++m) {
          asm("v_cvt_pk_bf16_f32 %0, %1, %2" : "=v"(ua[m]) : "v"(sA[4 * m]), "v"(sA[4 * m + 1]));
          asm("v_cvt_pk_bf16_f32 %0, %1, %2" : "=v"(va[m]) : "v"(sA[4 * m + 2]), "v"(sA[4 * m + 3]));
          asm("v_cvt_pk_bf16_f32 %0, %1, %2" : "=v"(ub[m]) : "v"(sB[4 * m]), "v"(sB[4 * m + 1]));
          asm("v_cvt_pk_bf16_f32 %0, %1, %2" : "=v"(vb[m]) : "v"(sB[4 * m + 2]), "v"(sB[4 * m + 3]));
        }
        asm("v_permlane32_swap_b32 %0, %1" : "+v"(ua[0]), "+v"(ua[1]));
        asm("v_permlane32_swap_b32 %0, %1" : "+v"(va[0]), "+v"(va[1]));
        asm("v_permlane32_swap_b32 %0, %1" : "+v"(ua[2]), "+v"(ua[3]));
        asm("v_permlane32_swap_b32 %0, %1" : "+v"(va[2]), "+v"(va[3]));
        asm("v_permlane32_swap_b32 %0, %1" : "+v"(ub[0]), "+v"(ub[1]));
        asm("v_permlane32_swap_b32 %0, %1" : "+v"(vb[0]), "+v"(vb[1]));
        asm("v_permlane32_swap_b32 %0, %1" : "+v"(ub[2]), "+v"(ub[3]));
        asm("v_permlane32_swap_b32 %0, %1" : "+v"(vb[2]), "+v"(vb[3]));
        u32x4 w0 = {ua[0], va[0], ua[1], va[1]};
        u32x4 w1 = {ua[2], va[2], ua[3], va[3]};
        u32x4 w2 = {ub[0], vb[0], ub[1], vb[1]};
        u32x4 w3 = {ub[2], vb[2], ub[3], vb[3]};
        bf16x8 pf0 = __builtin_bit_cast(bf16x8, w0);
        bf16x8 pf1 = __builtin_bit_cast(bf16x8, w1);
        bf16x8 pf2 = __builtin_bit_cast(bf16x8, w2);
        bf16x8 pf3 = __builtin_bit_cast(bf16x8, w3);
        __builtin_amdgcn_s_setprio(1);
        {
          bf16x8 v0 = *reinterpret_cast<const bf16x8*>(&Vs[buf][off + 0 * 512 + lane * 8]);
          bf16x8 v4 = *reinterpret_cast<const bf16x8*>(&Vs[buf][off + 4 * 512 + lane * 8]);
          oA = __builtin_amdgcn_mfma_f32_32x32x16_bf16(v0, pf0, oA, 0, 0, 0);
          oB = __builtin_amdgcn_mfma_f32_32x32x16_bf16(v4, pf0, oB, 0, 0, 0);
          bf16x8 v1 = *reinterpret_cast<const bf16x8*>(&Vs[buf][off + 1 * 512 + lane * 8]);
          bf16x8 v5 = *reinterpret_cast<const bf16x8*>(&Vs[buf][off + 5 * 512 + lane * 8]);
          oA = __builtin_amdgcn_mfma_f32_32x32x16_bf16(v1, pf1, oA, 0, 0, 0);
          oB = __builtin_amdgcn_mfma_f32_32x32x16_bf16(v5, pf1, oB, 0, 0, 0);
          bf16x8 v2 = *reinterpret_cast<const bf16x8*>(&Vs[buf][off + 2 * 512 + lane * 8]);
          bf16x8 v6 = *reinterpret_cast<const bf16x8*>(&Vs[buf][off + 6 * 512 + lane * 8]);
          oA = __builtin_amdgcn_mfma_f32_32x32x16_bf16(v2, pf2, oA, 0, 0, 0);
          oB = __builtin_amdgcn_mfma_f32_32x32x16_bf16(v6, pf2, oB, 0, 0, 0);
          bf16x8 v3 = *reinterpret_cast<const bf16x8*>(&Vs[buf][off + 3 * 512 + lane * 8]);
          bf16x8 v7 = *reinterpret_cast<const bf16x8*>(&Vs[buf][off + 7 * 512 + lane * 8]);
          oA = __builtin_amdgcn_mfma_f32_32x32x16_bf16(v3, pf3, oA, 0, 0, 0);
          oB = __builtin_amdgcn_mfma_f32_32x32x16_bf16(v7, pf3, oB, 0, 0, 0);
        }
        __builtin_amdgcn_s_setprio(0);
      }
    }
    __syncthreads();  // all reads of buf done + my gloads for buf^1 landed
    buf ^= 1;
  }

  const float inv = 1.0f / lrun;
  const size_t obase = ((size_t)b * T_SEQ + qrow) * CDIM + h * HD;
#pragma unroll
  for (int g2 = 0; g2 < 4; ++g2) {
    us4 pa, pb;
#pragma unroll
    for (int jj = 0; jj < 4; ++jj) {
      pa[jj] = f2bf(oA[4 * g2 + jj] * inv);
      pb[jj] = f2bf(oB[4 * g2 + jj] * inv);
    }
    *reinterpret_cast<us4*>(&att[obase + g2 * 8 + 4 * hi]) = pa;
    *reinterpret_cast<us4*>(&att[obase + 32 + g2 * 8 + 4 * hi]) = pb;
  }
}

extern "C" void kernel_launch(void* const* d_in, const int* in_sizes, int n_in,
                              void* d_out, int out_size, void* d_ws, size_t ws_size,
                              hipStream_t stream) {
  const float* x = (const float*)d_in[0];
  const float* Wq = (const float*)d_in[1];
  const float* Wkv = (const float*)d_in[2];
  const float* Wc = (const float*)d_in[3];
  float* out = (float*)d_out;

  char* ws = (char*)d_ws;
  size_t off = 0;
  auto alloc = [&](size_t bytes) {
    void* p = ws + off;
    off += (bytes + 255) & ~(size_t)255;
    return p;
  };
  const size_t NTOK = 4ull * T_SEQ;            // 8192
  const size_t NELEM = NTOK * CDIM;            // 8388608
  unsigned short* xb = (unsigned short*)alloc(NELEM * 2);   // also reused for att
  unsigned short* WT = (unsigned short*)alloc(3072ull * 1024 * 2);
  unsigned short* WcT = (unsigned short*)alloc(1024ull * 1024 * 2);
  unsigned short* qb = (unsigned short*)alloc(NELEM * 2);
  unsigned short* kb = (unsigned short*)alloc(NELEM * 2);
  unsigned short* vT = (unsigned short*)alloc(NELEM * 2);
  float* cost = (float*)alloc(T_SEQ * 32 * 4);
  float* sint = (float*)alloc(T_SEQ * 32 * 4);
  unsigned short* att = xb;  // xb dead after gemm<1>; reuse for attention output

  cast_x_kernel<<<(int)(NELEM / 4 / 256), 256, 0, stream>>>(x, xb, (int)(NELEM / 4));
  transpose_cast_all_kernel<<<dim3(128, 32), 256, 0, stream>>>(Wq, Wkv, Wc, WT, WcT);
  rope_table_kernel<<<T_SEQ * 32 / 256, 256, 0, stream>>>(cost, sint);

  gemm_kernel<1><<<dim3(3072 / 128, NTOK / 128), 256, 0, stream>>>(
      xb, WT, (int)NTOK, 3072, 1024, qb, kb, vT, cost, sint, nullptr);

  attn_kernel<<<dim3(512), 512, 0, stream>>>(qb, kb, vT, att);

  gemm_kernel<0><<<dim3(1024 / 128, NTOK / 128), 256, 0, stream>>>(
      att, WcT, (int)NTOK, 1024, 1024, nullptr, nullptr, nullptr, nullptr, nullptr, out);
}

// Round 19
// 167.048 us; speedup vs baseline: 1.0736x; 1.0736x over previous
//
#include <hip/hip_runtime.h>
#include <math.h>

typedef __attribute__((ext_vector_type(4))) float f32x4;
typedef __attribute__((ext_vector_type(16))) float f32x16;
typedef __attribute__((ext_vector_type(8))) short bf16x8;
typedef __attribute__((ext_vector_type(4))) unsigned short us4;
typedef __attribute__((ext_vector_type(4))) unsigned int u32x4;

#define T_SEQ 2048
#define NH 16
#define HD 64
#define CDIM 1024

__device__ __forceinline__ unsigned short f2bf(float f) {
  unsigned int u = __float_as_uint(f);
  u += 0x7fffu + ((u >> 16) & 1u);
  return (unsigned short)(u >> 16);
}

__device__ __forceinline__ f32x16 zero16() {
  f32x16 z;
#pragma unroll
  for (int i = 0; i < 16; ++i) z[i] = 0.0f;
  return z;
}

// global -> LDS direct (16B/lane, wave-uniform LDS base + lane*16)
#define GLOAD_LDS(g, l)                                                   \
  __builtin_amdgcn_global_load_lds(                                       \
      (const __attribute__((address_space(1))) unsigned int*)(g),         \
      (__attribute__((address_space(3))) unsigned int*)(l), 16, 0, 0)

// ---------------- cast x: fp32 -> bf16 ----------------
__global__ __launch_bounds__(256) void cast_x_kernel(const float* __restrict__ src,
                                                     unsigned short* __restrict__ dst,
                                                     int n4) {
  int i = blockIdx.x * 256 + threadIdx.x;
  if (i >= n4) return;
  f32x4 v = reinterpret_cast<const f32x4*>(src)[i];
  us4 o;
#pragma unroll
  for (int j = 0; j < 4; ++j) o[j] = f2bf(v[j]);
  reinterpret_cast<us4*>(dst)[i] = o;
}

// -------- fused transpose+cast of all 3 weights: W[K][N] fp32 -> W^T bf16 ----
__global__ __launch_bounds__(256) void transpose_cast_all_kernel(
    const float* __restrict__ Wq, const float* __restrict__ Wkv,
    const float* __restrict__ Wc, unsigned short* __restrict__ WT,
    unsigned short* __restrict__ WcT) {
  __shared__ float tile[32][33];
  const int nglob = blockIdx.x * 32;
  const float* src;
  unsigned short* dst;
  int ldsrc, n0;
  if (nglob < 1024) {
    src = Wq; dst = WT; ldsrc = 1024; n0 = nglob;
  } else if (nglob < 3072) {
    src = Wkv; dst = WT + 1024 * 1024; ldsrc = 2048; n0 = nglob - 1024;
  } else {
    src = Wc; dst = WcT; ldsrc = 1024; n0 = nglob - 3072;
  }
  const int k0 = blockIdx.y * 32;
  const int tx = threadIdx.x & 31, ty = threadIdx.x >> 5;  // 32x8
#pragma unroll
  for (int r = 0; r < 4; ++r)
    tile[ty + r * 8][tx] = src[(size_t)(k0 + ty + r * 8) * ldsrc + n0 + tx];
  __syncthreads();
#pragma unroll
  for (int r = 0; r < 4; ++r)
    dst[(size_t)(n0 + ty + r * 8) * 1024 + k0 + tx] = f2bf(tile[tx][ty + r * 8]);
}

// ---------------- RoPE table: cos/sin [T][32] fp32 ----------------
__global__ __launch_bounds__(256) void rope_table_kernel(float* __restrict__ cost,
                                                         float* __restrict__ sint) {
  int idx = blockIdx.x * 256 + threadIdx.x;  // 2048*32
  int t = idx >> 5, j = idx & 31;
  double invf = pow(10000.0, -(double)j / 32.0);
  double ang = (double)t * invf;
  cost[idx] = (float)cos(ang);
  sint[idx] = (float)sin(ang);
}

// ---------------- GEMM: C[M][N] = A[M][K] * B^T[N][K], bf16 in, fp32 acc ----
// 2-phase double-buffered pipeline (R9/R13/R17, attested 682 TF / 74.8us).
// BK=64, 2x32KB LDS. XOR col-block swizzle both-sides (rule 21) -> 0 bank
// conflicts (R8). REGRESSION LEDGER: R10 counted-vmcnt graft -28%; R14
// 8-phase port -17%; R18 BK=32 -17% (barrier count doubles, TLP can't cover).
// BK=64 2-phase is the session's robust local optimum — do not perturb.
template <int MODE>
__global__ __launch_bounds__(256) void gemm_kernel(
    const unsigned short* __restrict__ A, const unsigned short* __restrict__ Bt,
    int M, int N, int K,
    unsigned short* __restrict__ qo, unsigned short* __restrict__ ko,
    unsigned short* __restrict__ vTo, const float* __restrict__ cost,
    const float* __restrict__ sint, float* __restrict__ out) {
  __shared__ __align__(16) unsigned short As[2][128 * 64];  // 2 x 16KB
  __shared__ __align__(16) unsigned short Bs[2][128 * 64];  // 2 x 16KB
  const int tid = threadIdx.x;
  const int lane = tid & 63;
  const int wave = tid >> 6;
  const int wr = wave >> 1, wc = wave & 1;
  const int m0 = blockIdx.y * 128, n0 = blockIdx.x * 128;
  const int lrow = lane & 15, lhi = lane >> 4;
  const int srow = lane >> 3;                  // row within 8-row chunk
  const int scol = (((lane & 7) ^ srow) * 8);  // swizzled source col (elems)

  f32x4 zero4 = {0.f, 0.f, 0.f, 0.f};
  f32x4 acc[4][4];
#pragma unroll
  for (int mi = 0; mi < 4; ++mi)
#pragma unroll
    for (int ni = 0; ni < 4; ++ni) acc[mi][ni] = zero4;

  const int ntiles = K >> 6;  // BK=64
  auto stage = [&](int bf, int kt) {
#pragma unroll
    for (int c2 = 0; c2 < 4; ++c2) {
      const int c = wave * 4 + c2;  // chunk 0..15 (8 rows x 128B each)
      GLOAD_LDS(&A[(size_t)(m0 + c * 8 + srow) * K + kt + scol], &As[bf][c * 512]);
      GLOAD_LDS(&Bt[(size_t)(n0 + c * 8 + srow) * K + kt + scol], &Bs[bf][c * 512]);
    }
  };

  stage(0, 0);
  __syncthreads();  // buf0 ready
  int cur = 0;
  for (int ti = 0; ti < ntiles; ++ti) {
    if (ti + 1 < ntiles) stage(cur ^ 1, (ti + 1) * 64);  // in flight under compute
#pragma unroll
    for (int kk = 0; kk < 2; ++kk) {
      bf16x8 af[4], bfv[4];
#pragma unroll
      for (int i = 0; i < 4; ++i) {
        const int ra = wr * 64 + i * 16 + lrow;
        const int rb = wc * 64 + i * 16 + lrow;
        const int cba = (kk * 4 + lhi) ^ (ra & 7);  // un-swizzle on read
        const int cbb = (kk * 4 + lhi) ^ (rb & 7);
        af[i] = *reinterpret_cast<const bf16x8*>(&As[cur][ra * 64 + cba * 8]);
        bfv[i] = *reinterpret_cast<const bf16x8*>(&Bs[cur][rb * 64 + cbb * 8]);
      }
#pragma unroll
      for (int mi = 0; mi < 4; ++mi)
#pragma unroll
        for (int ni = 0; ni < 4; ++ni)
          acc[mi][ni] =
              __builtin_amdgcn_mfma_f32_16x16x32_bf16(af[mi], bfv[ni], acc[mi][ni], 0, 0, 0);
    }
    __syncthreads();  // drains my gloads (flew under MFMA) + reads; swap safe
    cur ^= 1;
  }

  if (MODE == 0) {
#pragma unroll
    for (int mi = 0; mi < 4; ++mi)
#pragma unroll
      for (int ni = 0; ni < 4; ++ni) {
        int n = n0 + wc * 64 + ni * 16 + lrow;
#pragma unroll
        for (int r = 0; r < 4; ++r) {
          int m = m0 + wr * 64 + mi * 16 + lhi * 4 + r;
          out[(size_t)m * N + n] = acc[mi][ni][r];
        }
      }
  } else {
#pragma unroll
    for (int mi = 0; mi < 4; ++mi) {
      int mb = m0 + wr * 64 + mi * 16 + lhi * 4;  // 4 consecutive rows (t)
      int b = mb >> 11, tb = mb & (T_SEQ - 1);
#pragma unroll
      for (int ni = 0; ni < 4; ++ni) {
        int n = n0 + wc * 64 + ni * 16 + lrow;
        int sec = n >> 10;          // 0=q 1=k 2=v
        int h = (n >> 6) & 15;
        int d = n & 63;
        int bh_ = b * NH + h;
        if (sec == 2) {
          int t64 = tb >> 6, ks = (tb >> 4) & 3, hiv = (tb >> 3) & 1, e0 = tb & 7;
          int dgrp = d >> 5, lanev = hiv * 32 + (d & 31);
          us4 pk;
#pragma unroll
          for (int r = 0; r < 4; ++r) pk[r] = f2bf(acc[mi][ni][r]);
          size_t addr =
              ((((size_t)bh_ * 32 + t64) * 2 + dgrp) * 4 + ks) * 512 + lanev * 8 + e0;
          *reinterpret_cast<us4*>(&vTo[addr]) = pk;
        } else {
          int dm = d & 31;
          float sgn = (d < 32) ? -1.0f : 1.0f;
          unsigned short* dstp = (sec == 0) ? qo : ko;
          int ks = d >> 4, hiq = (d >> 3) & 1, e = d & 7;
#pragma unroll
          for (int r = 0; r < 4; ++r) {
            int t = tb + r;
            float c = cost[t * 32 + dm], s = sint[t * 32 + dm];
            float val = acc[mi][ni][r] * c + sgn * acc[mi][ni ^ 2][r] * s;
            if (sec == 0) val *= 0.125f;  // 1/sqrt(64) folded into q
            int blk = t >> 5, lane_ = hiq * 32 + (t & 31);
            dstp[(((size_t)bh_ * 64 + blk) * 4 + ks) * 512 + lane_ * 8 + e] = f2bf(val);
          }
        }
      }
    }
  }
}

// ---------------- flash attention, causal; 32x32 swapped-QK^T ----------------
// R15/R17 attested config: 8-wave/512-thread blocks, super-tile staging
// (128 keys / 32KB per stage, 2 x 64-key compute steps per barrier),
// double-buffered LDS (64KB -> 2 blocks/CU). In-register softmax; T13
// defer-max; T12 cvt_pk+permlane; setprio around MFMA. R16's pair-balanced
// variant REGRESSED: do not re-add.
__global__ __launch_bounds__(512, 2) void attn_kernel(const unsigned short* __restrict__ qg,
                                                      const unsigned short* __restrict__ kg,
                                                      const unsigned short* __restrict__ vtg,
                                                      unsigned short* __restrict__ att) {
  __shared__ __align__(16) unsigned short Ks[2][8192];  // 2 x 16KB (128 keys)
  __shared__ __align__(16) unsigned short Vs[2][8192];  // 2 x 16KB
  const int tid = threadIdx.x;
  const int lane = tid & 63;
  const int w = tid >> 6;
  const int l31 = lane & 31, hi = lane >> 5;
  const int bid = (int)blockIdx.x;          // 0..511
  const int second = bid >> 8;
  const int q = bid & 255;
  const int xcd = q & 7, g = q >> 3;
  const int bh = xcd * 8 + (g >> 2);
  const int ii = g & 3;
  const int i = second ? (7 - ii) : ii;
  const int pos = (w < 4) ? (4 * i + w) : (63 - 4 * i - (w - 4));
  const int qrow = pos * 32 + l31;
  const int myt = (pos >> 1) + 1;       // 64-key steps this wave needs
  const int maxT = 32 - 2 * i;          // block lockstep 64-key steps (even)
  const int smaxT = maxT >> 1;          // super-tiles (128 keys each)
  const unsigned short* qfp = qg + (size_t)bh * 131072;
  const unsigned short* kfp = kg + (size_t)bh * 131072;
  const unsigned short* vfp = vtg + (size_t)bh * 131072;
  const int b = bh >> 4, h = bh & 15;

  bf16x8 qf[4];
#pragma unroll
  for (int ks = 0; ks < 4; ++ks)
    qf[ks] = *reinterpret_cast<const bf16x8*>(&qfp[((size_t)pos * 4 + ks) * 512 + lane * 8]);

  f32x16 oA = zero16(), oB = zero16();
  float mrun = -3.0e38f, lrun = 0.0f;

  // super-tile T = keys 128T..128T+127 = 8192 contiguous elems (frag-major).
  auto stage = [&](int bf, int T) {
    GLOAD_LDS(&kfp[(size_t)T * 8192 + tid * 8], &Ks[bf][w * 512]);
    GLOAD_LDS(&kfp[(size_t)T * 8192 + 4096 + tid * 8], &Ks[bf][4096 + w * 512]);
    GLOAD_LDS(&vfp[(size_t)T * 8192 + tid * 8], &Vs[bf][w * 512]);
    GLOAD_LDS(&vfp[(size_t)T * 8192 + 4096 + tid * 8], &Vs[bf][4096 + w * 512]);
  };

  stage(0, 0);
  __syncthreads();
  int buf = 0;
  for (int T = 0; T < smaxT; ++T) {
    if (T + 1 < smaxT) stage(buf ^ 1, T + 1);  // 4 gloads fly under 2 steps
#pragma unroll
    for (int sub = 0; sub < 2; ++sub) {
      const int s = 2 * T + sub;  // 64-key step index
      const int off = sub * 4096;
      if (s < myt) {  // wave-uniform predicate
        f32x16 sA = zero16(), sB = zero16();
        __builtin_amdgcn_s_setprio(1);
#pragma unroll
        for (int ks = 0; ks < 4; ++ks) {
          bf16x8 ka = *reinterpret_cast<const bf16x8*>(&Ks[buf][off + ks * 512 + lane * 8]);
          bf16x8 kb =
              *reinterpret_cast<const bf16x8*>(&Ks[buf][off + (4 + ks) * 512 + lane * 8]);
          sA = __builtin_amdgcn_mfma_f32_32x32x16_bf16(ka, qf[ks], sA, 0, 0, 0);
          sB = __builtin_amdgcn_mfma_f32_32x32x16_bf16(kb, qf[ks], sB, 0, 0, 0);
        }
        __builtin_amdgcn_s_setprio(0);
        if (s == myt - 1) {  // only final step can contain future keys
          const int kvb = s * 64;
#pragma unroll
          for (int r = 0; r < 16; ++r) {
            int keyA = kvb + (r & 3) + 8 * (r >> 2) + 4 * hi;
            if (keyA > qrow) sA[r] = -1e30f;
            if (keyA + 32 > qrow) sB[r] = -1e30f;
          }
        }
        float tr[16];
#pragma unroll
        for (int k2 = 0; k2 < 16; ++k2) tr[k2] = fmaxf(sA[k2], sB[k2]);
#pragma unroll
        for (int k2 = 0; k2 < 8; ++k2) tr[k2] = fmaxf(tr[k2], tr[k2 + 8]);
#pragma unroll
        for (int k2 = 0; k2 < 4; ++k2) tr[k2] = fmaxf(tr[k2], tr[k2 + 4]);
        float tm = fmaxf(fmaxf(tr[0], tr[1]), fmaxf(tr[2], tr[3]));
        tm = fmaxf(tm, __shfl_xor(tm, 32));
        if (!__all(tm - mrun <= 8.0f)) {  // T13 defer-max
          float mnew = fmaxf(mrun, tm);
          float alpha = __expf(mrun - mnew);
          lrun *= alpha;
#pragma unroll
          for (int k2 = 0; k2 < 16; ++k2) {
            oA[k2] *= alpha;
            oB[k2] *= alpha;
          }
          mrun = mnew;
        }
#pragma unroll
        for (int k2 = 0; k2 < 16; ++k2) {
          sA[k2] = __expf(sA[k2] - mrun);
          sB[k2] = __expf(sB[k2] - mrun);
        }
        float sr[16];
#pragma unroll
        for (int k2 = 0; k2 < 16; ++k2) sr[k2] = sA[k2] + sB[k2];
#pragma unroll
        for (int k2 = 0; k2 < 8; ++k2) sr[k2] += sr[k2 + 8];
#pragma unroll
        for (int k2 = 0; k2 < 4; ++k2) sr[k2] += sr[k2 + 4];
        float lsum = (sr[0] + sr[1]) + (sr[2] + sr[3]);
        lsum += __shfl_xor(lsum, 32);
        lrun += lsum;
        // T12: P -> B-operand fragments in registers
        unsigned int ua[4], va[4], ub[4], vb[4];
#pragma unroll
        for (int m = 0; m < 4; ++m) {
          asm("v_cvt_pk_bf16_f32 %0, %1, %2" : "=v"(ua[m]) : "v"(sA[4 * m]), "v"(sA[4 * m + 1]));
          asm("v_cvt_pk_bf16_f32 %0, %1, %2" : "=v"(va[m]) : "v"(sA[4 * m + 2]), "v"(sA[4 * m + 3]));
          asm("v_cvt_pk_bf16_f32 %0, %1, %2" : "=v"(ub[m]) : "v"(sB[4 * m]), "v"(sB[4 * m + 1]));
          asm("v_cvt_pk_bf16_f32 %0, %1, %2" : "=v"(vb[m]) : "v"(sB[4 * m + 2]), "v"(sB[4 * m + 3]));
        }
        asm("v_permlane32_swap_b32 %0, %1" : "+v"(ua[0]), "+v"(ua[1]));
        asm("v_permlane32_swap_b32 %0, %1" : "+v"(va[0]), "+v"(va[1]));
        asm("v_permlane32_swap_b32 %0, %1" : "+v"(ua[2]), "+v"(ua[3]));
        asm("v_permlane32_swap_b32 %0, %1" : "+v"(va[2]), "+v"(va[3]));
        asm("v_permlane32_swap_b32 %0, %1" : "+v"(ub[0]), "+v"(ub[1]));
        asm("v_permlane32_swap_b32 %0, %1" : "+v"(vb[0]), "+v"(vb[1]));
        asm("v_permlane32_swap_b32 %0, %1" : "+v"(ub[2]), "+v"(ub[3]));
        asm("v_permlane32_swap_b32 %0, %1" : "+v"(vb[2]), "+v"(vb[3]));
        u32x4 w0 = {ua[0], va[0], ua[1], va[1]};
        u32x4 w1 = {ua[2], va[2], ua[3], va[3]};
        u32x4 w2 = {ub[0], vb[0], ub[1], vb[1]};
        u32x4 w3 = {ub[2], vb[2], ub[3], vb[3]};
        bf16x8 pf0 = __builtin_bit_cast(bf16x8, w0);
        bf16x8 pf1 = __builtin_bit_cast(bf16x8, w1);
        bf16x8 pf2 = __builtin_bit_cast(bf16x8, w2);
        bf16x8 pf3 = __builtin_bit_cast(bf16x8, w3);
        __builtin_amdgcn_s_setprio(1);
        {
          bf16x8 v0 = *reinterpret_cast<const bf16x8*>(&Vs[buf][off + 0 * 512 + lane * 8]);
          bf16x8 v4 = *reinterpret_cast<const bf16x8*>(&Vs[buf][off + 4 * 512 + lane * 8]);
          oA = __builtin_amdgcn_mfma_f32_32x32x16_bf16(v0, pf0, oA, 0, 0, 0);
          oB = __builtin_amdgcn_mfma_f32_32x32x16_bf16(v4, pf0, oB, 0, 0, 0);
          bf16x8 v1 = *reinterpret_cast<const bf16x8*>(&Vs[buf][off + 1 * 512 + lane * 8]);
          bf16x8 v5 = *reinterpret_cast<const bf16x8*>(&Vs[buf][off + 5 * 512 + lane * 8]);
          oA = __builtin_amdgcn_mfma_f32_32x32x16_bf16(v1, pf1, oA, 0, 0, 0);
          oB = __builtin_amdgcn_mfma_f32_32x32x16_bf16(v5, pf1, oB, 0, 0, 0);
          bf16x8 v2 = *reinterpret_cast<const bf16x8*>(&Vs[buf][off + 2 * 512 + lane * 8]);
          bf16x8 v6 = *reinterpret_cast<const bf16x8*>(&Vs[buf][off + 6 * 512 + lane * 8]);
          oA = __builtin_amdgcn_mfma_f32_32x32x16_bf16(v2, pf2, oA, 0, 0, 0);
          oB = __builtin_amdgcn_mfma_f32_32x32x16_bf16(v6, pf2, oB, 0, 0, 0);
          bf16x8 v3 = *reinterpret_cast<const bf16x8*>(&Vs[buf][off + 3 * 512 + lane * 8]);
          bf16x8 v7 = *reinterpret_cast<const bf16x8*>(&Vs[buf][off + 7 * 512 + lane * 8]);
          oA = __builtin_amdgcn_mfma_f32_32x32x16_bf16(v3, pf3, oA, 0, 0, 0);
          oB = __builtin_amdgcn_mfma_f32_32x32x16_bf16(v7, pf3, oB, 0, 0, 0);
        }
        __builtin_amdgcn_s_setprio(0);
      }
    }
    __syncthreads();  // all reads of buf done + my gloads for buf^1 landed
    buf ^= 1;
  }

  const float inv = 1.0f / lrun;
  const size_t obase = ((size_t)b * T_SEQ + qrow) * CDIM + h * HD;
#pragma unroll
  for (int g2 = 0; g2 < 4; ++g2) {
    us4 pa, pb;
#pragma unroll
    for (int jj = 0; jj < 4; ++jj) {
      pa[jj] = f2bf(oA[4 * g2 + jj] * inv);
      pb[jj] = f2bf(oB[4 * g2 + jj] * inv);
    }
    *reinterpret_cast<us4*>(&att[obase + g2 * 8 + 4 * hi]) = pa;
    *reinterpret_cast<us4*>(&att[obase + 32 + g2 * 8 + 4 * hi]) = pb;
  }
}

extern "C" void kernel_launch(void* const* d_in, const int* in_sizes, int n_in,
                              void* d_out, int out_size, void* d_ws, size_t ws_size,
                              hipStream_t stream) {
  const float* x = (const float*)d_in[0];
  const float* Wq = (const float*)d_in[1];
  const float* Wkv = (const float*)d_in[2];
  const float* Wc = (const float*)d_in[3];
  float* out = (float*)d_out;

  char* ws = (char*)d_ws;
  size_t off = 0;
  auto alloc = [&](size_t bytes) {
    void* p = ws + off;
    off += (bytes + 255) & ~(size_t)255;
    return p;
  };
  const size_t NTOK = 4ull * T_SEQ;            // 8192
  const size_t NELEM = NTOK * CDIM;            // 8388608
  unsigned short* xb = (unsigned short*)alloc(NELEM * 2);   // also reused for att
  unsigned short* WT = (unsigned short*)alloc(3072ull * 1024 * 2);
  unsigned short* WcT = (unsigned short*)alloc(1024ull * 1024 * 2);
  unsigned short* qb = (unsigned short*)alloc(NELEM * 2);
  unsigned short* kb = (unsigned short*)alloc(NELEM * 2);
  unsigned short* vT = (unsigned short*)alloc(NELEM * 2);
  float* cost = (float*)alloc(T_SEQ * 32 * 4);
  float* sint = (float*)alloc(T_SEQ * 32 * 4);
  unsigned short* att = xb;  // xb dead after gemm<1>; reuse for attention output

  cast_x_kernel<<<(int)(NELEM / 4 / 256), 256, 0, stream>>>(x, xb, (int)(NELEM / 4));
  transpose_cast_all_kernel<<<dim3(128, 32), 256, 0, stream>>>(Wq, Wkv, Wc, WT, WcT);
  rope_table_kernel<<<T_SEQ * 32 / 256, 256, 0, stream>>>(cost, sint);

  gemm_kernel<1><<<dim3(3072 / 128, NTOK / 128), 256, 0, stream>>>(
      xb, WT, (int)NTOK, 3072, 1024, qb, kb, vT, cost, sint, nullptr);

  attn_kernel<<<dim3(512), 512, 0, stream>>>(qb, kb, vT, att);

  gemm_kernel<0><<<dim3(1024 / 128, NTOK / 128), 256, 0, stream>>>(
      att, WcT, (int)NTOK, 1024, 1024, nullptr, nullptr, nullptr, nullptr, nullptr, out);
}